// Round 1
// baseline (6417.851 us; speedup 1.0000x reference)
//
#include <hip/hip_runtime.h>

#define N_NODESC 100000
#define N_EDGESC 250000
#define EMB 300
#define LD 304      // padded feature stride (multiple of 8 for GEMM K-chunks)
#define LD4 76      // LD/4 float4s
#define LAYERS 5
#define BN_EPS 1e-5f
#define MCHUNK 50000

__device__ __forceinline__ float4 f4add(float4 a, float4 b){
    return make_float4(a.x+b.x, a.y+b.y, a.z+b.z, a.w+b.w);
}

// ---------------- utility zero kernels (avoid memset in capture) -------------
__global__ void k_zero_i(int* p, int n){
    int i = blockIdx.x*blockDim.x + threadIdx.x;
    if(i < n) p[i] = 0;
}
__global__ void k_zero_f(float* p, int n){
    int i = blockIdx.x*blockDim.x + threadIdx.x;
    if(i < n) p[i] = 0.f;
}

// ---------------- atom encoder: h = emb1[x0] + emb2[x1], stride LD ----------
__global__ void k_atom(const int* __restrict__ x,
                       const float* __restrict__ e1,
                       const float* __restrict__ e2,
                       float* __restrict__ h){
    int idx = blockIdx.x*blockDim.x + threadIdx.x;
    if(idx >= N_NODESC*LD4) return;
    int i = idx / LD4, c = idx % LD4;
    float4 v = make_float4(0,0,0,0);
    if(c < 75){
        int i0 = x[2*i], i1 = x[2*i+1];
        const float4* r1 = (const float4*)(e1 + (size_t)i0*EMB);
        const float4* r2 = (const float4*)(e2 + (size_t)i1*EMB);
        v = f4add(r1[c], r2[c]);
    }
    ((float4*)h)[idx] = v;
}

// ---------------- combined edge-embedding table etab[l][ea0*3+ea1][LD] ------
__global__ void k_etab(const float* __restrict__ e1,
                       const float* __restrict__ e2,
                       float* __restrict__ etab){
    int idx = blockIdx.x*blockDim.x + threadIdx.x;
    if(idx >= LAYERS*18*LD4) return;
    int l = idx / (18*LD4);
    int r = idx % (18*LD4);
    int c = r / LD4, f = r % LD4;
    float4 v = make_float4(0,0,0,0);
    if(f < 75){
        const float4* r1 = (const float4*)(e1 + (size_t)(l*6 + c/3)*EMB);
        const float4* r2 = (const float4*)(e2 + (size_t)(l*3 + c%3)*EMB);
        v = f4add(r1[f], r2[f]);
    }
    ((float4*)etab)[idx] = v;
}

// ---------------- W1 padded copy: wp1[l][304][600], rows>=300 zero ----------
__global__ void k_padw1(const float* __restrict__ W1, float* __restrict__ wp){
    int idx = blockIdx.x*blockDim.x + threadIdx.x;
    if(idx >= LAYERS*LD*150) return;              // 150 float4s per 600-row
    int l = idx / (LD*150);
    int r = idx % (LD*150);
    int k = r / 150, f = r % 150;
    float4 v = make_float4(0,0,0,0);
    if(k < EMB) v = ((const float4*)(W1 + ((size_t)l*EMB + k)*600))[f];
    ((float4*)wp)[idx] = v;
}

// ---------------- CSR build -------------------------------------------------
__global__ void k_deg(const int* __restrict__ ei, int* __restrict__ deg){
    int e = blockIdx.x*blockDim.x + threadIdx.x;
    if(e >= N_EDGESC) return;
    atomicAdd(&deg[ei[N_EDGESC + e]], 1);
}

__global__ void k_scan(const int* __restrict__ deg,
                       int* __restrict__ offs, int* __restrict__ cursor){
    __shared__ int sh[1024];
    const int CH = (N_NODESC + 1023)/1024;        // 98
    int t = threadIdx.x;
    int base = t*CH;
    int s = 0;
    for(int i=0;i<CH;i++){ int j = base+i; if(j < N_NODESC) s += deg[j]; }
    sh[t] = s; __syncthreads();
    for(int off=1; off<1024; off<<=1){
        int v = (t >= off) ? sh[t-off] : 0;
        __syncthreads();
        sh[t] += v;
        __syncthreads();
    }
    int run = sh[t] - s;                          // exclusive prefix
    for(int i=0;i<CH;i++){
        int j = base+i;
        if(j < N_NODESC){ offs[j]=run; cursor[j]=run; run += deg[j]; }
    }
    if(t == 1023) offs[N_NODESC] = sh[1023];
}

__global__ void k_fill(const int* __restrict__ ei, const int* __restrict__ ea,
                       int* __restrict__ cursor,
                       int* __restrict__ csr_src, int* __restrict__ csr_ea){
    int e = blockIdx.x*blockDim.x + threadIdx.x;
    if(e >= N_EDGESC) return;
    int d = ei[N_EDGESC + e];
    int p = atomicAdd(&cursor[d], 1);
    csr_src[p] = ei[e];
    csr_ea[p]  = ea[2*e]*3 + ea[2*e+1];
}

// ---------------- gather-sum aggregation (atomic-free) ----------------------
__global__ void k_agg(const float* __restrict__ h, const float* __restrict__ etab_l,
                      const int* __restrict__ offs, const int* __restrict__ csr_src,
                      const int* __restrict__ csr_ea, float* __restrict__ agg){
    int idx = blockIdx.x*blockDim.x + threadIdx.x;
    if(idx >= N_NODESC*LD4) return;
    int i = idx / LD4, c = idx % LD4;
    const float4* h4 = (const float4*)h;
    const float4* et = (const float4*)etab_l;
    // self loop: attr (4,0) -> combined idx 12
    float4 acc = f4add(h4[(size_t)i*LD4 + c], et[12*LD4 + c]);
    int j0 = offs[i], j1 = offs[i+1];
    for(int j=j0; j<j1; j++){
        int s = csr_src[j];
        int t = csr_ea[j];
        acc = f4add(acc, f4add(h4[(size_t)s*LD4 + c], et[t*LD4 + c]));
    }
    ((float4*)agg)[idx] = acc;
}

// ---------------- fp32 tiled GEMM: C = act(A@B + bias) ----------------------
// A[M,K] lda, B[K,Nout] ldb, C[M,Nout] ldc.  128x128 tile, 8x8/thread, BK=8.
__global__ __launch_bounds__(256) void k_gemm(
    const float* __restrict__ A, int lda,
    const float* __restrict__ B, int ldb,
    const float* __restrict__ bias,
    float* __restrict__ C, int ldc,
    int M, int K, int Nout, int relu)
{
    __shared__ float As[8][128];
    __shared__ float Bs[8][128];
    int tid = threadIdx.x;
    int tx = tid & 15, ty = tid >> 4;
    int m0 = blockIdx.y*128, n0 = blockIdx.x*128;

    float acc[8][8];
    #pragma unroll
    for(int i=0;i<8;i++)
        #pragma unroll
        for(int j=0;j<8;j++) acc[i][j]=0.f;

    int arow = tid >> 1, acol = (tid & 1)*4;
    int brow = tid >> 5, bcol = (tid & 31)*4;
    int gmA = m0 + arow; if(gmA >= M) gmA = M-1;       // clamp; store-guarded
    const float* aptr = A + (size_t)gmA*lda + acol;
    const float* bptr = B + (size_t)brow*ldb + n0 + bcol;
    bool bvalid = (n0 + bcol) < Nout;                  // Nout % 4 == 0

    for(int kc=0; kc<K; kc+=8){
        float4 av = *(const float4*)(aptr + kc);
        float4 bv = make_float4(0,0,0,0);
        if(bvalid) bv = *(const float4*)(bptr + (size_t)kc*ldb);
        As[acol+0][arow]=av.x; As[acol+1][arow]=av.y;
        As[acol+2][arow]=av.z; As[acol+3][arow]=av.w;
        *(float4*)&Bs[brow][bcol] = bv;
        __syncthreads();
        #pragma unroll
        for(int k=0;k<8;k++){
            float a[8], bb[8];
            *(float4*)&a[0]  = *(const float4*)&As[k][ty*8];
            *(float4*)&a[4]  = *(const float4*)&As[k][ty*8+4];
            *(float4*)&bb[0] = *(const float4*)&Bs[k][tx*8];
            *(float4*)&bb[4] = *(const float4*)&Bs[k][tx*8+4];
            #pragma unroll
            for(int i=0;i<8;i++)
                #pragma unroll
                for(int j=0;j<8;j++)
                    acc[i][j] = fmaf(a[i], bb[j], acc[i][j]);
        }
        __syncthreads();
    }

    #pragma unroll
    for(int i=0;i<8;i++){
        int gm = m0 + ty*8 + i;
        if(gm >= M) continue;
        #pragma unroll
        for(int j=0;j<8;j+=4){
            int gn = n0 + tx*8 + j;
            if(gn >= Nout) continue;
            float4 v = make_float4(acc[i][j],acc[i][j+1],acc[i][j+2],acc[i][j+3]);
            float4 bs = *(const float4*)(bias + gn);
            v.x+=bs.x; v.y+=bs.y; v.z+=bs.z; v.w+=bs.w;
            if(relu){
                v.x=fmaxf(v.x,0.f); v.y=fmaxf(v.y,0.f);
                v.z=fmaxf(v.z,0.f); v.w=fmaxf(v.w,0.f);
            }
            *(float4*)(C + (size_t)gm*ldc + gn) = v;
        }
    }
}

// ---------------- BN column stats: sum & sumsq over N rows ------------------
__global__ void k_bnstats(const float* __restrict__ X, float* __restrict__ stats){
    int c = threadIdx.x;
    if(c >= EMB) return;
    int r0 = blockIdx.x*128;
    int rend = r0 + 128; if(rend > N_NODESC) rend = N_NODESC;
    float s = 0.f, q = 0.f;
    for(int r=r0; r<rend; r++){
        float v = X[(size_t)r*EMB + c];
        s += v; q += v*v;
    }
    atomicAdd(&stats[c], s);
    atomicAdd(&stats[EMB + c], q);
}

// ---------------- BN apply (+relu) ------------------------------------------
__global__ void k_bnapply(const float* __restrict__ X, const float* __restrict__ stats,
                          const float* __restrict__ g, const float* __restrict__ bt,
                          float* __restrict__ hn, float* __restrict__ dout,
                          int relu, int last){
    int idx = blockIdx.x*blockDim.x + threadIdx.x;
    if(idx >= N_NODESC*LD4) return;
    int i = idx / LD4, c = idx % LD4;
    if(c == 75){
        if(!last) ((float4*)hn)[idx] = make_float4(0,0,0,0);
        return;
    }
    const float4* X4 = (const float4*)X;
    float4 v  = X4[(size_t)i*75 + c];
    float4 s  = ((const float4*)stats)[c];
    float4 q  = ((const float4*)stats)[75 + c];
    float4 gg = ((const float4*)g)[c];
    float4 bb = ((const float4*)bt)[c];
    const float inv_n = 1.0f/(float)N_NODESC;
    #define BN1(f) { float m = s.f*inv_n; float var = q.f*inv_n - m*m;          \
                     float r = rsqrtf(var + BN_EPS);                             \
                     v.f = (v.f - m)*r*gg.f + bb.f;                              \
                     if(relu) v.f = fmaxf(v.f, 0.f); }
    BN1(x) BN1(y) BN1(z) BN1(w)
    #undef BN1
    if(last) ((float4*)dout)[(size_t)i*75 + c] = v;
    else     ((float4*)hn)[idx] = v;
}

// ----------------------------------------------------------------------------
extern "C" void kernel_launch(void* const* d_in, const int* in_sizes, int n_in,
                              void* d_out, int out_size, void* d_ws, size_t ws_size,
                              hipStream_t stream) {
    const int*   x     = (const int*)d_in[0];
    const int*   ei    = (const int*)d_in[1];
    const int*   ea    = (const int*)d_in[2];
    const float* aemb1 = (const float*)d_in[3];
    const float* aemb2 = (const float*)d_in[4];
    const float* eemb1 = (const float*)d_in[5];
    const float* eemb2 = (const float*)d_in[6];
    const float* W1    = (const float*)d_in[7];
    const float* b1    = (const float*)d_in[8];
    const float* W2    = (const float*)d_in[9];
    const float* b2    = (const float*)d_in[10];
    const float* gamma = (const float*)d_in[11];
    const float* beta  = (const float*)d_in[12];
    float* dout = (float*)d_out;

    // workspace layout (floats), total ~370 MB
    float* ws   = (float*)d_ws;
    float* h    = ws;
    float* agg  = h    + (size_t)N_NODESC*LD;           // 30.4M f
    float* hmid = agg  + (size_t)N_NODESC*LD;           // 30.4M f
    float* wp1  = hmid + (size_t)MCHUNK*600;            // 30.0M f
    float* etab = wp1  + (size_t)LAYERS*LD*600;         // 912k f
    float* stats= etab + (size_t)LAYERS*18*LD;          // 27.36k f
    int*   deg     = (int*)(stats + 640);
    int*   offs    = deg    + N_NODESC;
    int*   cursor  = offs   + N_NODESC + 1;
    int*   csr_src = cursor + N_NODESC + 1;
    int*   csr_ea  = csr_src + N_EDGESC;

    const int nb_nf4 = (N_NODESC*LD4 + 255)/256;

    // one-time (per call) setup
    k_atom<<<nb_nf4, 256, 0, stream>>>(x, aemb1, aemb2, h);
    k_etab<<<(LAYERS*18*LD4 + 255)/256, 256, 0, stream>>>(eemb1, eemb2, etab);
    k_padw1<<<(LAYERS*LD*150 + 255)/256, 256, 0, stream>>>(W1, wp1);
    k_zero_i<<<(N_NODESC + 255)/256, 256, 0, stream>>>(deg, N_NODESC);
    k_deg<<<(N_EDGESC + 255)/256, 256, 0, stream>>>(ei, deg);
    k_scan<<<1, 1024, 0, stream>>>(deg, offs, cursor);
    k_fill<<<(N_EDGESC + 255)/256, 256, 0, stream>>>(ei, ea, cursor, csr_src, csr_ea);

    for(int l=0; l<LAYERS; l++){
        k_agg<<<nb_nf4, 256, 0, stream>>>(h, etab + (size_t)l*18*LD,
                                          offs, csr_src, csr_ea, agg);
        for(int ch=0; ch<2; ch++){
            const float* Ag = agg + (size_t)ch*MCHUNK*LD;
            float* Co = dout + (size_t)ch*MCHUNK*EMB;
            dim3 g1(5, (MCHUNK + 127)/128);     // Nout=600 -> 5 tiles
            k_gemm<<<g1, 256, 0, stream>>>(Ag, LD, wp1 + (size_t)l*LD*600, 600,
                                           b1 + (size_t)l*600, hmid, 600,
                                           MCHUNK, LD, 600, 1);
            dim3 g2(3, (MCHUNK + 127)/128);     // Nout=300 -> 3 tiles
            k_gemm<<<g2, 256, 0, stream>>>(hmid, 600, W2 + (size_t)l*600*300, 300,
                                           b2 + (size_t)l*300, Co, 300,
                                           MCHUNK, 600, 300, 0);
        }
        k_zero_f<<<(2*EMB + 255)/256, 256, 0, stream>>>(stats, 2*EMB);
        k_bnstats<<<(N_NODESC + 127)/128, 320, 0, stream>>>(dout, stats);
        k_bnapply<<<nb_nf4, 256, 0, stream>>>(dout, stats,
                                              gamma + (size_t)l*EMB, beta + (size_t)l*EMB,
                                              h, dout, (l < LAYERS-1) ? 1 : 0,
                                              (l == LAYERS-1) ? 1 : 0);
    }
}

// Round 2
// 2574.742 us; speedup vs baseline: 2.4926x; 2.4926x over previous
//
#include <hip/hip_runtime.h>
#include <hip/hip_bf16.h>

#define N_NODESC 100000
#define N_EDGESC 250000
#define EMB 300
#define LD 304      // fp32 h / etab stride (float4-friendly)
#define LD4 76
#define LAYERS 5
#define BN_EPS 1e-5f

#define K1 320      // padded K for GEMM1 (agg stride)
#define N1 640      // padded N for GEMM1 (hmid stride, = K for GEMM2)
#define K2 640
#define N2 384      // padded N for GEMM2 (output guarded to 300)

typedef __attribute__((ext_vector_type(8))) short short8;
typedef __attribute__((ext_vector_type(4))) float f32x4;

#define GLOAD16(g, l) __builtin_amdgcn_global_load_lds( \
    (const __attribute__((address_space(1))) void*)(g), \
    (__attribute__((address_space(3))) void*)(l), 16, 0, 0)

__device__ __forceinline__ float4 f4add(float4 a, float4 b){
    return make_float4(a.x+b.x, a.y+b.y, a.z+b.z, a.w+b.w);
}
__device__ __forceinline__ unsigned short f2bf(float f){
    __hip_bfloat16 h = __float2bfloat16(f);
    return *(unsigned short*)&h;
}

// ---------------- utility zero kernels --------------------------------------
__global__ void k_zero_i(int* p, int n){
    int i = blockIdx.x*blockDim.x + threadIdx.x;
    if(i < n) p[i] = 0;
}
__global__ void k_zero_f(float* p, int n){
    int i = blockIdx.x*blockDim.x + threadIdx.x;
    if(i < n) p[i] = 0.f;
}

// ---------------- atom encoder: h = emb1[x0] + emb2[x1], fp32 stride LD -----
__global__ void k_atom(const int* __restrict__ x,
                       const float* __restrict__ e1,
                       const float* __restrict__ e2,
                       float* __restrict__ h){
    int idx = blockIdx.x*blockDim.x + threadIdx.x;
    if(idx >= N_NODESC*LD4) return;
    int i = idx / LD4, c = idx % LD4;
    float4 v = make_float4(0,0,0,0);
    if(c < 75){
        int i0 = x[2*i], i1 = x[2*i+1];
        const float4* r1 = (const float4*)(e1 + (size_t)i0*EMB);
        const float4* r2 = (const float4*)(e2 + (size_t)i1*EMB);
        v = f4add(r1[c], r2[c]);
    }
    ((float4*)h)[idx] = v;
}

// ---------------- combined edge-embedding table etab[l][ea0*3+ea1][LD] ------
__global__ void k_etab(const float* __restrict__ e1,
                       const float* __restrict__ e2,
                       float* __restrict__ etab){
    int idx = blockIdx.x*blockDim.x + threadIdx.x;
    if(idx >= LAYERS*18*LD4) return;
    int l = idx / (18*LD4);
    int r = idx % (18*LD4);
    int c = r / LD4, f = r % LD4;
    float4 v = make_float4(0,0,0,0);
    if(f < 75){
        const float4* r1 = (const float4*)(e1 + (size_t)(l*6 + c/3)*EMB);
        const float4* r2 = (const float4*)(e2 + (size_t)(l*3 + c%3)*EMB);
        v = f4add(r1[f], r2[f]);
    }
    ((float4*)etab)[idx] = v;
}

// ---------------- weight prep: B^T padded bf16 ------------------------------
// wb1t[l][n][k], n<N1, k<K1 : W1[l][k][n] if (n<600 && k<300) else 0
__global__ void k_prepw1(const float* __restrict__ W1, unsigned short* __restrict__ wb){
    int idx = blockIdx.x*blockDim.x + threadIdx.x;
    if(idx >= LAYERS*N1*K1) return;
    int l = idx / (N1*K1);
    int r = idx % (N1*K1);
    int n = r / K1, k = r % K1;
    float v = (n < 600 && k < EMB) ? W1[((size_t)l*EMB + k)*600 + n] : 0.f;
    wb[idx] = f2bf(v);
}
// wb2t[l][n][k], n<N2, k<K2 : W2[l][k][n] if (n<300 && k<600) else 0
__global__ void k_prepw2(const float* __restrict__ W2, unsigned short* __restrict__ wb){
    int idx = blockIdx.x*blockDim.x + threadIdx.x;
    if(idx >= LAYERS*N2*K2) return;
    int l = idx / (N2*K2);
    int r = idx % (N2*K2);
    int n = r / K2, k = r % K2;
    float v = (n < EMB && k < 600) ? W2[((size_t)l*600 + k)*EMB + n] : 0.f;
    wb[idx] = f2bf(v);
}
// bias1p[l][N1], zero pad past 600
__global__ void k_prepb1(const float* __restrict__ b1, float* __restrict__ bp){
    int idx = blockIdx.x*blockDim.x + threadIdx.x;
    if(idx >= LAYERS*N1) return;
    int l = idx / N1, n = idx % N1;
    bp[idx] = (n < 600) ? b1[(size_t)l*600 + n] : 0.f;
}

// ---------------- CSR build -------------------------------------------------
__global__ void k_deg(const int* __restrict__ ei, int* __restrict__ deg){
    int e = blockIdx.x*blockDim.x + threadIdx.x;
    if(e >= N_EDGESC) return;
    atomicAdd(&deg[ei[N_EDGESC + e]], 1);
}

__global__ void k_scan(const int* __restrict__ deg,
                       int* __restrict__ offs, int* __restrict__ cursor){
    __shared__ int sh[1024];
    const int CH = (N_NODESC + 1023)/1024;
    int t = threadIdx.x;
    int base = t*CH;
    int s = 0;
    for(int i=0;i<CH;i++){ int j = base+i; if(j < N_NODESC) s += deg[j]; }
    sh[t] = s; __syncthreads();
    for(int off=1; off<1024; off<<=1){
        int v = (t >= off) ? sh[t-off] : 0;
        __syncthreads();
        sh[t] += v;
        __syncthreads();
    }
    int run = sh[t] - s;
    for(int i=0;i<CH;i++){
        int j = base+i;
        if(j < N_NODESC){ offs[j]=run; cursor[j]=run; run += deg[j]; }
    }
    if(t == 1023) offs[N_NODESC] = sh[1023];
}

__global__ void k_fill(const int* __restrict__ ei, const int* __restrict__ ea,
                       int* __restrict__ cursor,
                       int* __restrict__ csr_src, int* __restrict__ csr_ea){
    int e = blockIdx.x*blockDim.x + threadIdx.x;
    if(e >= N_EDGESC) return;
    int d = ei[N_EDGESC + e];
    int p = atomicAdd(&cursor[d], 1);
    csr_src[p] = ei[e];
    csr_ea[p]  = ea[2*e]*3 + ea[2*e+1];
}

// ---------------- gather-sum aggregation -> bf16 agg[i][K1] -----------------
__global__ void k_agg(const float* __restrict__ h, const float* __restrict__ etab_l,
                      const int* __restrict__ offs, const int* __restrict__ csr_src,
                      const int* __restrict__ csr_ea, unsigned short* __restrict__ agg){
    int idx = blockIdx.x*blockDim.x + threadIdx.x;
    if(idx >= N_NODESC*80) return;          // 80 chunks of 4 cols = 320
    int i = idx / 80, c = idx % 80;
    ushort4 out;
    if(c < 75){
        const float4* h4 = (const float4*)h;
        const float4* et = (const float4*)etab_l;
        // self loop: attr (4,0) -> combined idx 12
        float4 acc = f4add(h4[(size_t)i*LD4 + c], et[12*LD4 + c]);
        int j0 = offs[i], j1 = offs[i+1];
        for(int j=j0; j<j1; j++){
            int s = csr_src[j];
            int t = csr_ea[j];
            acc = f4add(acc, f4add(h4[(size_t)s*LD4 + c], et[t*LD4 + c]));
        }
        out.x = f2bf(acc.x); out.y = f2bf(acc.y);
        out.z = f2bf(acc.z); out.w = f2bf(acc.w);
    } else {
        out.x = out.y = out.z = out.w = 0;
    }
    *(ushort4*)(agg + (size_t)i*K1 + c*4) = out;
}

// ---------------- bf16 MFMA GEMM: C = epi(A @ Bt^T + bias) ------------------
// A [M][K] bf16 (row stride K), Bt [Npad][K] bf16 (row stride K).
// 128x128 tile, 4 waves, each 64x64 (4x4 frags of 16x16), BK=32.
// EPI 0: bf16 store, +bias, relu, stride ldc.  EPI 1: fp32 store, +bias, col<300.
template<int EPI>
__global__ __launch_bounds__(256) void k_mgemm(
    const unsigned short* __restrict__ A,
    const unsigned short* __restrict__ Bt,
    const float* __restrict__ bias,
    void* __restrict__ Cptr, int M, int K, int ldc)
{
    __shared__ unsigned short As[128*32];
    __shared__ unsigned short Bs[128*32];
    int tid = threadIdx.x;
    int wv = tid >> 6, ln = tid & 63;
    int m0 = blockIdx.y*128, n0 = blockIdx.x*128;
    int wm = (wv >> 1)*64, wn = (wv & 1)*64;

    // staging: chunk c (16B = 8 bf16) -> row c>>2, cols (c&3)*8..+7
    int ar0 = tid >> 2, ar1 = ar0 + 64;
    int aq  = (tid & 3)*8;
    int ra0 = m0 + ar0; if(ra0 >= M) ra0 = M-1;
    int ra1 = m0 + ar1; if(ra1 >= M) ra1 = M-1;
    const unsigned short* srcA0 = A  + (size_t)ra0*K + aq;
    const unsigned short* srcA1 = A  + (size_t)ra1*K + aq;
    const unsigned short* srcB0 = Bt + (size_t)(n0 + ar0)*K + aq;
    const unsigned short* srcB1 = Bt + (size_t)(n0 + ar1)*K + aq;
    char* dA0 = (char*)As + (size_t)(wv*64)*16;
    char* dA1 = (char*)As + (size_t)(256 + wv*64)*16;
    char* dB0 = (char*)Bs + (size_t)(wv*64)*16;
    char* dB1 = (char*)Bs + (size_t)(256 + wv*64)*16;

    int lr = ln & 15, lk = (ln >> 4)*8;

    f32x4 acc[4][4] = {};

    for(int kc = 0; kc < K; kc += 32){
        GLOAD16(srcA0 + kc, dA0);
        GLOAD16(srcA1 + kc, dA1);
        GLOAD16(srcB0 + kc, dB0);
        GLOAD16(srcB1 + kc, dB1);
        __syncthreads();                      // vmcnt(0) drain + barrier
        short8 av[4], bv[4];
        #pragma unroll
        for(int m=0;m<4;m++)
            av[m] = *(const short8*)(As + (size_t)(wm + m*16 + lr)*32 + lk);
        #pragma unroll
        for(int n=0;n<4;n++)
            bv[n] = *(const short8*)(Bs + (size_t)(wn + n*16 + lr)*32 + lk);
        #pragma unroll
        for(int m=0;m<4;m++)
            #pragma unroll
            for(int n=0;n<4;n++)
                acc[m][n] = __builtin_amdgcn_mfma_f32_16x16x32_bf16(
                                av[m], bv[n], acc[m][n], 0, 0, 0);
        __syncthreads();
    }

    // epilogue: C row = m0+wm+m*16+(ln>>4)*4+j, col = n0+wn+n*16+lr
    int rbase = m0 + wm + (ln >> 4)*4;
    if(EPI == 0){
        unsigned short* Cb = (unsigned short*)Cptr;
        #pragma unroll
        for(int n=0;n<4;n++){
            int col = n0 + wn + n*16 + lr;
            float bsv = bias[col];
            #pragma unroll
            for(int m=0;m<4;m++){
                #pragma unroll
                for(int j=0;j<4;j++){
                    int row = rbase + m*16 + j;
                    if(row < M){
                        float v = acc[m][n][j] + bsv;
                        Cb[(size_t)row*ldc + col] = f2bf(fmaxf(v, 0.f));
                    }
                }
            }
        }
    } else {
        float* Cf = (float*)Cptr;
        #pragma unroll
        for(int n=0;n<4;n++){
            int col = n0 + wn + n*16 + lr;
            if(col >= EMB) continue;
            float bsv = bias[col];
            #pragma unroll
            for(int m=0;m<4;m++){
                #pragma unroll
                for(int j=0;j<4;j++){
                    int row = rbase + m*16 + j;
                    if(row < M)
                        Cf[(size_t)row*ldc + col] = acc[m][n][j] + bsv;
                }
            }
        }
    }
}

// ---------------- BN column stats -------------------------------------------
__global__ void k_bnstats(const float* __restrict__ X, float* __restrict__ stats){
    int c = threadIdx.x;
    if(c >= EMB) return;
    int r0 = blockIdx.x*128;
    int rend = r0 + 128; if(rend > N_NODESC) rend = N_NODESC;
    float s = 0.f, q = 0.f;
    for(int r=r0; r<rend; r++){
        float v = X[(size_t)r*EMB + c];
        s += v; q += v*v;
    }
    atomicAdd(&stats[c], s);
    atomicAdd(&stats[EMB + c], q);
}

// ---------------- BN apply (+relu) ------------------------------------------
__global__ void k_bnapply(const float* __restrict__ X, const float* __restrict__ stats,
                          const float* __restrict__ g, const float* __restrict__ bt,
                          float* __restrict__ hn, float* __restrict__ dout,
                          int relu, int last){
    int idx = blockIdx.x*blockDim.x + threadIdx.x;
    if(idx >= N_NODESC*LD4) return;
    int i = idx / LD4, c = idx % LD4;
    if(c == 75){
        if(!last) ((float4*)hn)[idx] = make_float4(0,0,0,0);
        return;
    }
    const float4* X4 = (const float4*)X;
    float4 v  = X4[(size_t)i*75 + c];
    float4 s  = ((const float4*)stats)[c];
    float4 q  = ((const float4*)stats)[75 + c];
    float4 gg = ((const float4*)g)[c];
    float4 bb = ((const float4*)bt)[c];
    const float inv_n = 1.0f/(float)N_NODESC;
    #define BN1(f) { float m = s.f*inv_n; float var = q.f*inv_n - m*m;          \
                     float r = rsqrtf(var + BN_EPS);                             \
                     v.f = (v.f - m)*r*gg.f + bb.f;                              \
                     if(relu) v.f = fmaxf(v.f, 0.f); }
    BN1(x) BN1(y) BN1(z) BN1(w)
    #undef BN1
    if(last) ((float4*)dout)[(size_t)i*75 + c] = v;
    else     ((float4*)hn)[idx] = v;
}

// ----------------------------------------------------------------------------
extern "C" void kernel_launch(void* const* d_in, const int* in_sizes, int n_in,
                              void* d_out, int out_size, void* d_ws, size_t ws_size,
                              hipStream_t stream) {
    const int*   x     = (const int*)d_in[0];
    const int*   ei    = (const int*)d_in[1];
    const int*   ea    = (const int*)d_in[2];
    const float* aemb1 = (const float*)d_in[3];
    const float* aemb2 = (const float*)d_in[4];
    const float* eemb1 = (const float*)d_in[5];
    const float* eemb2 = (const float*)d_in[6];
    const float* W1    = (const float*)d_in[7];
    const float* b1    = (const float*)d_in[8];
    const float* W2    = (const float*)d_in[9];
    const float* b2    = (const float*)d_in[10];
    const float* gamma = (const float*)d_in[11];
    const float* beta  = (const float*)d_in[12];
    float* dout = (float*)d_out;

    // workspace layout
    float* h      = (float*)d_ws;                              // 100000*304 f
    float* bias1p = h + (size_t)N_NODESC*LD;                   // 5*640 f
    float* etab   = bias1p + LAYERS*N1;                        // 5*18*304 f
    float* stats  = etab + LAYERS*18*LD;                       // 640 f
    unsigned short* agg  = (unsigned short*)(stats + 640);     // 100000*320 bf16
    unsigned short* hmid = agg  + (size_t)N_NODESC*K1;         // 100000*640 bf16
    unsigned short* wb1t = hmid + (size_t)N_NODESC*N1;         // 5*640*320 bf16
    unsigned short* wb2t = wb1t + (size_t)LAYERS*N1*K1;        // 5*384*640 bf16
    int*   deg     = (int*)(wb2t + (size_t)LAYERS*N2*K2);
    int*   offs    = deg    + N_NODESC;
    int*   cursor  = offs   + N_NODESC + 1;
    int*   csr_src = cursor + N_NODESC + 1;
    int*   csr_ea  = csr_src + N_EDGESC;

    const int nb_nf4 = (N_NODESC*LD4 + 255)/256;

    // one-time setup
    k_atom<<<nb_nf4, 256, 0, stream>>>(x, aemb1, aemb2, h);
    k_etab<<<(LAYERS*18*LD4 + 255)/256, 256, 0, stream>>>(eemb1, eemb2, etab);
    k_prepw1<<<(LAYERS*N1*K1 + 255)/256, 256, 0, stream>>>(W1, wb1t);
    k_prepw2<<<(LAYERS*N2*K2 + 255)/256, 256, 0, stream>>>(W2, wb2t);
    k_prepb1<<<(LAYERS*N1 + 255)/256, 256, 0, stream>>>(b1, bias1p);
    k_zero_i<<<(N_NODESC + 255)/256, 256, 0, stream>>>(deg, N_NODESC);
    k_deg<<<(N_EDGESC + 255)/256, 256, 0, stream>>>(ei, deg);
    k_scan<<<1, 1024, 0, stream>>>(deg, offs, cursor);
    k_fill<<<(N_EDGESC + 255)/256, 256, 0, stream>>>(ei, ea, cursor, csr_src, csr_ea);

    const int MT = (N_NODESC + 127)/128;   // 782 M-tiles
    for(int l=0; l<LAYERS; l++){
        k_agg<<<(N_NODESC*80 + 255)/256, 256, 0, stream>>>(
            h, etab + (size_t)l*18*LD, offs, csr_src, csr_ea, agg);
        k_mgemm<0><<<dim3(N1/128, MT), 256, 0, stream>>>(
            agg, wb1t + (size_t)l*N1*K1, bias1p + (size_t)l*N1,
            hmid, N_NODESC, K1, N1);
        k_mgemm<1><<<dim3(N2/128, MT), 256, 0, stream>>>(
            hmid, wb2t + (size_t)l*N2*K2, b2 + (size_t)l*EMB,
            dout, N_NODESC, K2, EMB);
        k_zero_f<<<(2*EMB + 255)/256, 256, 0, stream>>>(stats, 2*EMB);
        k_bnstats<<<(N_NODESC + 127)/128, 320, 0, stream>>>(dout, stats);
        k_bnapply<<<nb_nf4, 256, 0, stream>>>(dout, stats,
                                              gamma + (size_t)l*EMB, beta + (size_t)l*EMB,
                                              h, dout, (l < LAYERS-1) ? 1 : 0,
                                              (l == LAYERS-1) ? 1 : 0);
    }
}

// Round 3
// 2098.599 us; speedup vs baseline: 3.0582x; 1.2269x over previous
//
#include <hip/hip_runtime.h>
#include <hip/hip_bf16.h>

#define N_NODESC 100000
#define N_EDGESC 250000
#define EMB 300
#define LD 304      // fp32 h / etab stride (float4-friendly)
#define LD4 76
#define LAYERS 5
#define BN_EPS 1e-5f

#define K1 320      // padded K for GEMM1 (agg stride)
#define N1 640      // padded N for GEMM1 (hmid stride, = K for GEMM2)
#define K2 640
#define N2 384      // padded N for GEMM2 (output guarded to 300)

#define NB_SCAN 391 // ceil(100000/256)

typedef __attribute__((ext_vector_type(8))) short short8;
typedef __attribute__((ext_vector_type(4))) float f32x4;

#define GLOAD16(g, l) __builtin_amdgcn_global_load_lds( \
    (const __attribute__((address_space(1))) void*)(g), \
    (__attribute__((address_space(3))) void*)(l), 16, 0, 0)

__device__ __forceinline__ float4 f4add(float4 a, float4 b){
    return make_float4(a.x+b.x, a.y+b.y, a.z+b.z, a.w+b.w);
}
__device__ __forceinline__ unsigned short f2bf(float f){
    __hip_bfloat16 h = __float2bfloat16(f);
    return *(unsigned short*)&h;
}

// ---------------- utility zero kernels --------------------------------------
__global__ void k_zero_i(int* p, int n){
    int i = blockIdx.x*blockDim.x + threadIdx.x;
    if(i < n) p[i] = 0;
}
__global__ void k_zero_f(float* p, int n){
    int i = blockIdx.x*blockDim.x + threadIdx.x;
    if(i < n) p[i] = 0.f;
}

// ---------------- atom encoder: h = emb1[x0] + emb2[x1], fp32 stride LD -----
__global__ void k_atom(const int* __restrict__ x,
                       const float* __restrict__ e1,
                       const float* __restrict__ e2,
                       float* __restrict__ h){
    int idx = blockIdx.x*blockDim.x + threadIdx.x;
    if(idx >= N_NODESC*LD4) return;
    int i = idx / LD4, c = idx % LD4;
    float4 v = make_float4(0,0,0,0);
    if(c < 75){
        int i0 = x[2*i], i1 = x[2*i+1];
        const float4* r1 = (const float4*)(e1 + (size_t)i0*EMB);
        const float4* r2 = (const float4*)(e2 + (size_t)i1*EMB);
        v = f4add(r1[c], r2[c]);
    }
    ((float4*)h)[idx] = v;
}

// ---------------- combined edge-embedding table etab[l][ea0*3+ea1][LD] ------
__global__ void k_etab(const float* __restrict__ e1,
                       const float* __restrict__ e2,
                       float* __restrict__ etab){
    int idx = blockIdx.x*blockDim.x + threadIdx.x;
    if(idx >= LAYERS*18*LD4) return;
    int l = idx / (18*LD4);
    int r = idx % (18*LD4);
    int c = r / LD4, f = r % LD4;
    float4 v = make_float4(0,0,0,0);
    if(f < 75){
        const float4* r1 = (const float4*)(e1 + (size_t)(l*6 + c/3)*EMB);
        const float4* r2 = (const float4*)(e2 + (size_t)(l*3 + c%3)*EMB);
        v = f4add(r1[f], r2[f]);
    }
    ((float4*)etab)[idx] = v;
}

// ---------------- weight prep: B^T padded bf16 ------------------------------
__global__ void k_prepw1(const float* __restrict__ W1, unsigned short* __restrict__ wb){
    int idx = blockIdx.x*blockDim.x + threadIdx.x;
    if(idx >= LAYERS*N1*K1) return;
    int l = idx / (N1*K1);
    int r = idx % (N1*K1);
    int n = r / K1, k = r % K1;
    float v = (n < 600 && k < EMB) ? W1[((size_t)l*EMB + k)*600 + n] : 0.f;
    wb[idx] = f2bf(v);
}
__global__ void k_prepw2(const float* __restrict__ W2, unsigned short* __restrict__ wb){
    int idx = blockIdx.x*blockDim.x + threadIdx.x;
    if(idx >= LAYERS*N2*K2) return;
    int l = idx / (N2*K2);
    int r = idx % (N2*K2);
    int n = r / K2, k = r % K2;
    float v = (n < EMB && k < 600) ? W2[((size_t)l*600 + k)*EMB + n] : 0.f;
    wb[idx] = f2bf(v);
}
__global__ void k_prepb1(const float* __restrict__ b1, float* __restrict__ bp){
    int idx = blockIdx.x*blockDim.x + threadIdx.x;
    if(idx >= LAYERS*N1) return;
    int l = idx / N1, n = idx % N1;
    bp[idx] = (n < 600) ? b1[(size_t)l*600 + n] : 0.f;
}

// ---------------- CSR build -------------------------------------------------
__global__ void k_deg(const int* __restrict__ ei, int* __restrict__ deg){
    int e = blockIdx.x*blockDim.x + threadIdx.x;
    if(e >= N_EDGESC) return;
    atomicAdd(&deg[ei[N_EDGESC + e]], 1);
}

// stage 1: per-block sums of 256 degrees
__global__ void k_bsum(const int* __restrict__ deg, int* __restrict__ bsum){
    int g = blockIdx.x*256 + threadIdx.x;
    int v = (g < N_NODESC) ? deg[g] : 0;
    #pragma unroll
    for(int o=32;o>0;o>>=1) v += __shfl_down(v, o);
    __shared__ int sw[4];
    if((threadIdx.x & 63) == 0) sw[threadIdx.x>>6] = v;
    __syncthreads();
    if(threadIdx.x == 0) bsum[blockIdx.x] = sw[0]+sw[1]+sw[2]+sw[3];
}

// stage 2: exclusive scan of NB_SCAN block sums (single tiny block)
__global__ void k_bscan(const int* __restrict__ bsum, int* __restrict__ bpre,
                        int* __restrict__ offs){
    __shared__ int sh[512];
    int t = threadIdx.x;
    int v = (t < NB_SCAN) ? bsum[t] : 0;
    sh[t] = v; __syncthreads();
    for(int o=1;o<512;o<<=1){
        int u = (t >= o) ? sh[t-o] : 0;
        __syncthreads();
        sh[t] += u;
        __syncthreads();
    }
    if(t < NB_SCAN) bpre[t] = sh[t] - v;
    if(t == NB_SCAN-1) offs[N_NODESC] = sh[t];
}

// stage 3: per-block exclusive scan + block prefix
__global__ void k_offs(const int* __restrict__ deg, const int* __restrict__ bpre,
                       int* __restrict__ offs, int* __restrict__ cursor){
    __shared__ int sh[256];
    int t = threadIdx.x;
    int g = blockIdx.x*256 + t;
    int v = (g < N_NODESC) ? deg[g] : 0;
    sh[t] = v; __syncthreads();
    for(int o=1;o<256;o<<=1){
        int u = (t >= o) ? sh[t-o] : 0;
        __syncthreads();
        sh[t] += u;
        __syncthreads();
    }
    if(g < N_NODESC){
        int e = bpre[blockIdx.x] + sh[t] - v;
        offs[g] = e; cursor[g] = e;
    }
}

__global__ void k_fill(const int* __restrict__ ei, const int* __restrict__ ea,
                       int* __restrict__ cursor,
                       int* __restrict__ csr_src, int* __restrict__ csr_ea){
    int e = blockIdx.x*blockDim.x + threadIdx.x;
    if(e >= N_EDGESC) return;
    int d = ei[N_EDGESC + e];
    int p = atomicAdd(&cursor[d], 1);
    csr_src[p] = ei[e];
    csr_ea[p]  = ea[2*e]*3 + ea[2*e+1];
}

// ---------------- gather-sum aggregation -> bf16 agg[i][K1] -----------------
__global__ void k_agg(const float* __restrict__ h, const float* __restrict__ etab_l,
                      const int* __restrict__ offs, const int* __restrict__ csr_src,
                      const int* __restrict__ csr_ea, unsigned short* __restrict__ agg){
    int idx = blockIdx.x*blockDim.x + threadIdx.x;
    if(idx >= N_NODESC*80) return;
    int i = idx / 80, c = idx % 80;
    ushort4 out;
    if(c < 75){
        const float4* h4 = (const float4*)h;
        const float4* et = (const float4*)etab_l;
        float4 acc = f4add(h4[(size_t)i*LD4 + c], et[12*LD4 + c]);
        int j0 = offs[i], j1 = offs[i+1];
        for(int j=j0; j<j1; j++){
            int s = csr_src[j];
            int t = csr_ea[j];
            acc = f4add(acc, f4add(h4[(size_t)s*LD4 + c], et[t*LD4 + c]));
        }
        out.x = f2bf(acc.x); out.y = f2bf(acc.y);
        out.z = f2bf(acc.z); out.w = f2bf(acc.w);
    } else {
        out.x = out.y = out.z = out.w = 0;
    }
    *(ushort4*)(agg + (size_t)i*K1 + c*4) = out;
}

// ---------------- bf16 MFMA GEMM: C = epi(A @ Bt^T + bias) ------------------
// EPI 0: bf16 store, +bias, relu.   EPI 1: fp32 store, +bias, col<300,
//        and fused BN column stats (sum, sumsq) via shfl+LDS+atomicAdd.
template<int EPI>
__global__ __launch_bounds__(256) void k_mgemm(
    const unsigned short* __restrict__ A,
    const unsigned short* __restrict__ Bt,
    const float* __restrict__ bias,
    void* __restrict__ Cptr, int M, int K, int ldc,
    float* __restrict__ stats)
{
    __shared__ unsigned short As[128*32];
    __shared__ unsigned short Bs[128*32];
    int tid = threadIdx.x;
    int wv = tid >> 6, ln = tid & 63;
    int m0 = blockIdx.y*128, n0 = blockIdx.x*128;
    int wm = (wv >> 1)*64, wn = (wv & 1)*64;

    int ar0 = tid >> 2, ar1 = ar0 + 64;
    int aq  = (tid & 3)*8;
    int ra0 = m0 + ar0; if(ra0 >= M) ra0 = M-1;
    int ra1 = m0 + ar1; if(ra1 >= M) ra1 = M-1;
    const unsigned short* srcA0 = A  + (size_t)ra0*K + aq;
    const unsigned short* srcA1 = A  + (size_t)ra1*K + aq;
    const unsigned short* srcB0 = Bt + (size_t)(n0 + ar0)*K + aq;
    const unsigned short* srcB1 = Bt + (size_t)(n0 + ar1)*K + aq;
    char* dA0 = (char*)As + (size_t)(wv*64)*16;
    char* dA1 = (char*)As + (size_t)(256 + wv*64)*16;
    char* dB0 = (char*)Bs + (size_t)(wv*64)*16;
    char* dB1 = (char*)Bs + (size_t)(256 + wv*64)*16;

    int lr = ln & 15, lk = (ln >> 4)*8;

    f32x4 acc[4][4] = {};

    for(int kc = 0; kc < K; kc += 32){
        GLOAD16(srcA0 + kc, dA0);
        GLOAD16(srcA1 + kc, dA1);
        GLOAD16(srcB0 + kc, dB0);
        GLOAD16(srcB1 + kc, dB1);
        __syncthreads();
        short8 av[4], bv[4];
        #pragma unroll
        for(int m=0;m<4;m++)
            av[m] = *(const short8*)(As + (size_t)(wm + m*16 + lr)*32 + lk);
        #pragma unroll
        for(int n=0;n<4;n++)
            bv[n] = *(const short8*)(Bs + (size_t)(wn + n*16 + lr)*32 + lk);
        #pragma unroll
        for(int m=0;m<4;m++)
            #pragma unroll
            for(int n=0;n<4;n++)
                acc[m][n] = __builtin_amdgcn_mfma_f32_16x16x32_bf16(
                                av[m], bv[n], acc[m][n], 0, 0, 0);
        __syncthreads();
    }

    // epilogue: C row = m0+wm+m*16+(ln>>4)*4+j, col = n0+wn+n*16+lr
    int rbase = m0 + wm + (ln >> 4)*4;
    if(EPI == 0){
        unsigned short* Cb = (unsigned short*)Cptr;
        #pragma unroll
        for(int n=0;n<4;n++){
            int col = n0 + wn + n*16 + lr;
            float bsv = bias[col];
            #pragma unroll
            for(int m=0;m<4;m++){
                #pragma unroll
                for(int j=0;j<4;j++){
                    int row = rbase + m*16 + j;
                    if(row < M){
                        float v = acc[m][n][j] + bsv;
                        Cb[(size_t)row*ldc + col] = f2bf(fmaxf(v, 0.f));
                    }
                }
            }
        }
    } else {
        float* Cf = (float*)Cptr;
        __shared__ float red[4][16][2];
        #pragma unroll
        for(int n=0;n<4;n++){
            int col = n0 + wn + n*16 + lr;
            bool cok = (col < EMB);
            float bsv = cok ? bias[col] : 0.f;
            float s = 0.f, q = 0.f;
            #pragma unroll
            for(int m=0;m<4;m++){
                #pragma unroll
                for(int j=0;j<4;j++){
                    int row = rbase + m*16 + j;
                    if(row < M){
                        float v = acc[m][n][j] + bsv;
                        if(cok){
                            Cf[(size_t)row*ldc + col] = v;
                            s += v; q += v*v;
                        }
                    }
                }
            }
            // reduce across the 4 lanes sharing this column (hi = ln>>4)
            s += __shfl_xor(s, 16); q += __shfl_xor(q, 16);
            s += __shfl_xor(s, 32); q += __shfl_xor(q, 32);
            if((ln >> 4) == 0){ red[wv][lr][0] = s; red[wv][lr][1] = q; }
            __syncthreads();
            if(wv < 2 && ln < 16){
                float S = red[wv][ln][0] + red[wv+2][ln][0];
                float Q = red[wv][ln][1] + red[wv+2][ln][1];
                int c2 = n0 + wv*64 + n*16 + ln;
                if(c2 < EMB){
                    atomicAdd(&stats[c2], S);
                    atomicAdd(&stats[EMB + c2], Q);
                }
            }
            __syncthreads();
        }
    }
}

// ---------------- BN apply (+relu) ------------------------------------------
__global__ void k_bnapply(const float* __restrict__ X, const float* __restrict__ stats,
                          const float* __restrict__ g, const float* __restrict__ bt,
                          float* __restrict__ hn, float* __restrict__ dout,
                          int relu, int last){
    int idx = blockIdx.x*blockDim.x + threadIdx.x;
    if(idx >= N_NODESC*LD4) return;
    int i = idx / LD4, c = idx % LD4;
    if(c == 75){
        if(!last) ((float4*)hn)[idx] = make_float4(0,0,0,0);
        return;
    }
    const float4* X4 = (const float4*)X;
    float4 v  = X4[(size_t)i*75 + c];
    float4 s  = ((const float4*)stats)[c];
    float4 q  = ((const float4*)stats)[75 + c];
    float4 gg = ((const float4*)g)[c];
    float4 bb = ((const float4*)bt)[c];
    const float inv_n = 1.0f/(float)N_NODESC;
    #define BN1(f) { float m = s.f*inv_n; float var = q.f*inv_n - m*m;          \
                     float r = rsqrtf(var + BN_EPS);                             \
                     v.f = (v.f - m)*r*gg.f + bb.f;                              \
                     if(relu) v.f = fmaxf(v.f, 0.f); }
    BN1(x) BN1(y) BN1(z) BN1(w)
    #undef BN1
    if(last) ((float4*)dout)[(size_t)i*75 + c] = v;
    else     ((float4*)hn)[idx] = v;
}

// ----------------------------------------------------------------------------
extern "C" void kernel_launch(void* const* d_in, const int* in_sizes, int n_in,
                              void* d_out, int out_size, void* d_ws, size_t ws_size,
                              hipStream_t stream) {
    const int*   x     = (const int*)d_in[0];
    const int*   ei    = (const int*)d_in[1];
    const int*   ea    = (const int*)d_in[2];
    const float* aemb1 = (const float*)d_in[3];
    const float* aemb2 = (const float*)d_in[4];
    const float* eemb1 = (const float*)d_in[5];
    const float* eemb2 = (const float*)d_in[6];
    const float* W1    = (const float*)d_in[7];
    const float* b1    = (const float*)d_in[8];
    const float* W2    = (const float*)d_in[9];
    const float* b2    = (const float*)d_in[10];
    const float* gamma = (const float*)d_in[11];
    const float* beta  = (const float*)d_in[12];
    float* dout = (float*)d_out;

    // workspace layout
    float* h      = (float*)d_ws;                              // 100000*304 f
    float* bias1p = h + (size_t)N_NODESC*LD;                   // 5*640 f
    float* etab   = bias1p + LAYERS*N1;                        // 5*18*304 f
    float* stats  = etab + LAYERS*18*LD;                       // 640 f
    unsigned short* agg  = (unsigned short*)(stats + 640);     // 100000*320 bf16
    unsigned short* hmid = agg  + (size_t)N_NODESC*K1;         // 100000*640 bf16
    unsigned short* wb1t = hmid + (size_t)N_NODESC*N1;         // 5*640*320 bf16
    unsigned short* wb2t = wb1t + (size_t)LAYERS*N1*K1;        // 5*384*640 bf16
    int*   deg     = (int*)(wb2t + (size_t)LAYERS*N2*K2);
    int*   offs    = deg    + N_NODESC;
    int*   cursor  = offs   + N_NODESC + 1;
    int*   csr_src = cursor + N_NODESC + 1;
    int*   csr_ea  = csr_src + N_EDGESC;
    int*   bsum    = csr_ea + N_EDGESC;
    int*   bpre    = bsum + NB_SCAN;

    const int nb_nf4 = (N_NODESC*LD4 + 255)/256;

    // one-time setup
    k_atom<<<nb_nf4, 256, 0, stream>>>(x, aemb1, aemb2, h);
    k_etab<<<(LAYERS*18*LD4 + 255)/256, 256, 0, stream>>>(eemb1, eemb2, etab);
    k_prepw1<<<(LAYERS*N1*K1 + 255)/256, 256, 0, stream>>>(W1, wb1t);
    k_prepw2<<<(LAYERS*N2*K2 + 255)/256, 256, 0, stream>>>(W2, wb2t);
    k_prepb1<<<(LAYERS*N1 + 255)/256, 256, 0, stream>>>(b1, bias1p);
    k_zero_i<<<(N_NODESC + 255)/256, 256, 0, stream>>>(deg, N_NODESC);
    k_deg<<<(N_EDGESC + 255)/256, 256, 0, stream>>>(ei, deg);
    k_bsum<<<NB_SCAN, 256, 0, stream>>>(deg, bsum);
    k_bscan<<<1, 512, 0, stream>>>(bsum, bpre, offs);
    k_offs<<<NB_SCAN, 256, 0, stream>>>(deg, bpre, offs, cursor);
    k_fill<<<(N_EDGESC + 255)/256, 256, 0, stream>>>(ei, ea, cursor, csr_src, csr_ea);

    const int MT = (N_NODESC + 127)/128;   // 782 M-tiles
    for(int l=0; l<LAYERS; l++){
        k_agg<<<(N_NODESC*80 + 255)/256, 256, 0, stream>>>(
            h, etab + (size_t)l*18*LD, offs, csr_src, csr_ea, agg);
        k_zero_f<<<(2*EMB + 255)/256, 256, 0, stream>>>(stats, 2*EMB);
        k_mgemm<0><<<dim3(N1/128, MT), 256, 0, stream>>>(
            agg, wb1t + (size_t)l*N1*K1, bias1p + (size_t)l*N1,
            hmid, N_NODESC, K1, N1, nullptr);
        k_mgemm<1><<<dim3(N2/128, MT), 256, 0, stream>>>(
            hmid, wb2t + (size_t)l*N2*K2, b2 + (size_t)l*EMB,
            dout, N_NODESC, K2, EMB, stats);
        k_bnapply<<<nb_nf4, 256, 0, stream>>>(dout, stats,
                                              gamma + (size_t)l*EMB, beta + (size_t)l*EMB,
                                              h, dout, (l < LAYERS-1) ? 1 : 0,
                                              (l == LAYERS-1) ? 1 : 0);
    }
}